// Round 6
// baseline (380.937 us; speedup 1.0000x reference)
//
#include <hip/hip_runtime.h>
#include <stdint.h>

// Problem dims
#define Bdim 32
#define Ndim 4096
#define Cin  64
#define Cout 64
#define Demb 16

typedef __bf16 bf16x8 __attribute__((ext_vector_type(8)));
typedef float  f32x4  __attribute__((ext_vector_type(4)));

#define GLOBAL_AS(p) ((__attribute__((address_space(1))) void*)(p))
#define LDS_AS(p)    ((__attribute__((address_space(3))) void*)(p))
#define GLL(gp, lp)  __builtin_amdgcn_global_load_lds(GLOBAL_AS(gp), LDS_AS(lp), 16, 0, 0)

__device__ __forceinline__ uint16_t f2bf(float x) {
    union { float f; uint32_t u; } v; v.f = x;
    uint32_t r = v.u + 0x7FFFu + ((v.u >> 16) & 1u);   // RNE, finite inputs
    return (uint16_t)(r >> 16);
}

__device__ __forceinline__ bf16x8 pack8(float4 a, float4 b) {
    union { uint16_t u[8]; bf16x8 v; } r;
    r.u[0] = f2bf(a.x); r.u[1] = f2bf(a.y); r.u[2] = f2bf(a.z); r.u[3] = f2bf(a.w);
    r.u[4] = f2bf(b.x); r.u[5] = f2bf(b.y); r.u[6] = f2bf(b.z); r.u[7] = f2bf(b.w);
    return r.v;
}

// ---------------------------------------------------------------------------
// P1: fused independent prep (blockIdx-partitioned roles, all 256-thread):
//   [0,1024)     k1: A~[n][m] = bf16(exp(relu(E[n]·E[m]))) UNNORMALIZED.
//                    4-way column-split; partial rowsums -> rs4[n][chunk]
//   [1024,3072)  k2: Xtt[b*64+c][m] = bf16(x[b][m][c])  (LDS tile transpose)
//   [3072,7168)  k4a: sd[n] = rsqrt(rowsum(adj[n]) + 0.5)
//   [7168,7232)  k5a: poolT[d][o*128+ki] = pool[d][ki*64+o]
// ---------------------------------------------------------------------------
__global__ __launch_bounds__(256) void p1_prep(const float* __restrict__ E,
                                               const float* __restrict__ x,
                                               const float* __restrict__ adj,
                                               const float* __restrict__ pool,
                                               uint16_t* __restrict__ A,
                                               float* __restrict__ rs4,
                                               uint16_t* __restrict__ Xtt,
                                               float* __restrict__ sd,
                                               float* __restrict__ poolT) {
    __shared__ __align__(16) uint8_t smem[9232];
    const int t = threadIdx.x;
    const int blk = blockIdx.x;

    if (blk < 1024) {
        // ---- k1: dynamic adjacency, 16 rows x 1024 cols per block ----
        float* Er_s = (float*)smem;            // 16x16
        float* red_s = (float*)(smem + 1024);  // 4
        const int n0 = (blk >> 2) * 16;
        const int chunk = blk & 3;
        const int m0 = chunk * 1024;
        Er_s[t] = E[n0 * Demb + t];
        __syncthreads();
        for (int half = 0; half < 2; ++half) {
            float er[8][16];
#pragma unroll
            for (int r = 0; r < 8; ++r)
#pragma unroll
                for (int d = 0; d < 16; ++d) er[r][d] = Er_s[(half * 8 + r) * 16 + d];
            float sacc[8];
#pragma unroll
            for (int r = 0; r < 8; ++r) sacc[r] = 0.f;
            for (int c = 0; c < 4; ++c) {
                const int m = m0 + c * 256 + t;
                const float4* ep = (const float4*)(E + (size_t)m * Demb);
                float4 e0 = ep[0], e1 = ep[1], e2 = ep[2], e3 = ep[3];
                float em[16] = {e0.x, e0.y, e0.z, e0.w, e1.x, e1.y, e1.z, e1.w,
                                e2.x, e2.y, e2.z, e2.w, e3.x, e3.y, e3.z, e3.w};
#pragma unroll
                for (int r = 0; r < 8; ++r) {
                    float v = 0.f;
#pragma unroll
                    for (int d = 0; d < 16; ++d) v = fmaf(er[r][d], em[d], v);
                    v = fmaxf(v, 0.f);
                    const float e = __expf(v);
                    sacc[r] += e;
                    A[(size_t)(n0 + half * 8 + r) * Ndim + m] = f2bf(e);
                }
            }
#pragma unroll
            for (int r = 0; r < 8; ++r) {
                float s = sacc[r];
#pragma unroll
                for (int off = 32; off > 0; off >>= 1) s += __shfl_down(s, off, 64);
                __syncthreads();
                if ((t & 63) == 0) red_s[t >> 6] = s;
                __syncthreads();
                if (t == 0)
                    rs4[(size_t)(n0 + half * 8 + r) * 4 + chunk] =
                        red_s[0] + red_s[1] + red_s[2] + red_s[3];
            }
            __syncthreads();
        }
    } else if (blk < 3072) {
        // ---- k2: x transpose to Xtt ----
        auto T = (uint16_t(*)[72])smem;
        const int idx = blk - 1024;
        const int m0 = (idx & 63) * 64;
        const int b = idx >> 6;
        const int c = t & 63;
#pragma unroll
        for (int j = 0; j < 16; ++j) {
            const int m = (t >> 6) + j * 4;
            T[c][m] = f2bf(x[((size_t)b * Ndim + (m0 + m)) * Cin + c]);
        }
        __syncthreads();
        const int c2 = t >> 2, mo = (t & 3) * 16;
        const uint4* src = (const uint4*)&T[c2][mo];
        uint4 v0 = src[0], v1 = src[1];
        uint4* dst = (uint4*)(Xtt + (size_t)(b * Cin + c2) * Ndim + m0 + mo);
        dst[0] = v0;
        dst[1] = v1;
    } else if (blk < 7168) {
        // ---- k4a: adj rowsum -> sd ----
        float* red_s = (float*)smem;
        const int n = blk - 3072;
        const float4* ap = (const float4*)(adj + (size_t)n * Ndim);
        float s = 0.f;
#pragma unroll
        for (int q = 0; q < 4; ++q) {
            float4 a = ap[q * 256 + t];
            s += a.x + a.y + a.z + a.w;
        }
#pragma unroll
        for (int off = 32; off > 0; off >>= 1) s += __shfl_down(s, off, 64);
        if ((t & 63) == 0) red_s[t >> 6] = s;
        __syncthreads();
        if (t == 0) sd[n] = sqrtf(1.f / (red_s[0] + red_s[1] + red_s[2] + red_s[3] + 0.5f));
    } else {
        // ---- k5a: pool transpose ----
        const int idx = blk - 7168;
        const int d = idx >> 2;
        const int base = (idx & 3) * 2048;
#pragma unroll
        for (int j = 0; j < 8; ++j) {
            const int e = base + j * 256 + t;          // e = ki*64 + o
            const float v = pool[d * 8192 + e];
            poolT[d * 8192 + (e & 63) * 128 + (e >> 6)] = v;
        }
    }
}

// ---------------------------------------------------------------------------
// P2: k4b + k5b + invA finalize.
//   [0,512)      k4b: partial colsum(rowsoftmax(rowsoftmax(sym-norm adj)))
//                R6: NO GLOBAL ATOMICS — per-block partials to pscale[blk][m]
//                (R5's 2.1M cross-XCD atomicAdds to 16 KiB were the 110 us:
//                 device-scope RMW line-bounce across 8 non-coherent L2s).
//                k6 folds the 512-partial reduction in-register.
//   [512,1536)   k5b: Wt[n][o*128+ki] = bf16(sum_d E[n,d]*poolT[d][...]); biasn
//   [1536,1552)  invA[n] = 1/sum(rs4[n][0..3])
// ---------------------------------------------------------------------------
__global__ __launch_bounds__(256) void p2_mid(const float* __restrict__ E,
                                              const float* __restrict__ adj,
                                              const float* __restrict__ sd,
                                              const float* __restrict__ poolT,
                                              const float* __restrict__ bias_pool,
                                              float* __restrict__ pscale,
                                              uint16_t* __restrict__ Wt,
                                              float* __restrict__ biasn,
                                              const float* __restrict__ rs4,
                                              float* __restrict__ invA) {
    __shared__ __align__(16) uint8_t smem[16384];
    const int t = threadIdx.x;
    const int blk = blockIdx.x;

    if (blk < 512) {
        // ---- k4b (2 rows per wave, partial colsums) ----
        float* cs = (float*)smem;                     // colsum accumulator [4096]
#pragma unroll
        for (int i = 0; i < 16; ++i) cs[i * 256 + t] = 0.f;
        __syncthreads();

        const int wv = t >> 6, l = t & 63;
        const int nb = blk * 8 + wv * 2;

        float sdm[64];
#pragma unroll
        for (int i = 0; i < 16; ++i) {
            float4 s4 = *(const float4*)(sd + i * 256 + l * 4);
            sdm[i * 4 + 0] = s4.x; sdm[i * 4 + 1] = s4.y;
            sdm[i * 4 + 2] = s4.z; sdm[i * 4 + 3] = s4.w;
        }
        float colsum[64];
#pragma unroll
        for (int k = 0; k < 64; ++k) colsum[k] = 0.f;

        for (int r = 0; r < 2; ++r) {
            const int n = nb + r;
            const float sdn = sd[n];
            float e1[64];
            float s1 = 0.f;
#pragma unroll
            for (int i = 0; i < 16; ++i) {
                float4 a4 = *(const float4*)(adj + (size_t)n * Ndim + i * 256 + l * 4);
                const int c0 = i * 256 + l * 4;
                float vv[4] = {a4.x, a4.y, a4.z, a4.w};
#pragma unroll
                for (int u = 0; u < 4; ++u) {
                    const float vd = vv[u] + ((c0 + u) == n ? 0.5f : 0.f);
                    const float e = __expf(sdn * vd * sdm[i * 4 + u]);
                    e1[i * 4 + u] = e;
                    s1 += e;
                }
            }
#pragma unroll
            for (int off = 32; off > 0; off >>= 1) s1 += __shfl_xor(s1, off, 64);
            const float inv1 = 1.f / s1;
            float s2 = 0.f;
#pragma unroll
            for (int k = 0; k < 64; ++k) {
                const float e = __expf(e1[k] * inv1);
                e1[k] = e;
                s2 += e;
            }
#pragma unroll
            for (int off = 32; off > 0; off >>= 1) s2 += __shfl_xor(s2, off, 64);
            const float inv2 = 1.f / s2;
#pragma unroll
            for (int k = 0; k < 64; ++k) colsum[k] = fmaf(e1[k], inv2, colsum[k]);
        }
        // combine waves in LDS (intra-block atomics: cheap), then ONE
        // coalesced plain-store pass of this block's partial colsum.
#pragma unroll
        for (int k = 0; k < 64; ++k)
            atomicAdd(&cs[(k >> 2) * 256 + l * 4 + (k & 3)], colsum[k]);
        __syncthreads();
#pragma unroll
        for (int i = 0; i < 16; ++i)
            pscale[(size_t)blk * 4096 + i * 256 + t] = cs[i * 256 + t];
    } else if (blk < 1536) {
        // ---- k5b ----
        float* En = (float*)smem;   // 32x16
        const int idx = blk - 512;
        const int ec = idx & 7;
        const int n0 = (idx >> 3) * 32;
        En[t] = E[n0 * Demb + t];
        En[t + 256] = E[n0 * Demb + t + 256];
        __syncthreads();

        const int e0 = ec * 1024 + t * 4;
        float4 P[16];
#pragma unroll
        for (int d = 0; d < 16; ++d) P[d] = *(const float4*)(poolT + d * 8192 + e0);

        for (int g = 0; g < 32; ++g) {
            float4 acc = {0.f, 0.f, 0.f, 0.f};
#pragma unroll
            for (int d = 0; d < 16; ++d) {
                const float e = En[g * 16 + d];
                acc.x = fmaf(e, P[d].x, acc.x);
                acc.y = fmaf(e, P[d].y, acc.y);
                acc.z = fmaf(e, P[d].z, acc.z);
                acc.w = fmaf(e, P[d].w, acc.w);
            }
            union { uint16_t u[4]; uint2 v; } r;
            r.u[0] = f2bf(acc.x); r.u[1] = f2bf(acc.y);
            r.u[2] = f2bf(acc.z); r.u[3] = f2bf(acc.w);
            *(uint2*)(Wt + (size_t)(n0 + g) * 8192 + e0) = r.v;
        }

        if (ec == 0) {
            const int o = t & 63, gq = t >> 6;
#pragma unroll
            for (int gi = 0; gi < 8; ++gi) {
                const int g = gi * 4 + gq;
                float a = 0.f;
#pragma unroll
                for (int d = 0; d < 16; ++d) a = fmaf(En[g * 16 + d], bias_pool[d * 64 + o], a);
                biasn[(size_t)(n0 + g) * 64 + o] = a;
            }
        }
    } else {
        // ---- invA finalize ----
        const int n = (blk - 1536) * 256 + t;
        const float4 v = *(const float4*)(rs4 + (size_t)n * 4);
        invA[n] = 1.f / (v.x + v.y + v.z + v.w);
    }
}

// ---------------------------------------------------------------------------
// K3 (R4-proven, frozen): XG[n][j] = invA[n] * sum_m A~[n][m] * Xtt[j][m]
// 128x128 tile, BK=64, dbuf, one __syncthreads per tile, XOR chunk swizzle,
// XCD-bijective block swizzle.  88.9 us / MfmaUtil 32% measured (R4).
// ---------------------------------------------------------------------------
#define GK 4096
#define GN 2048
#define K3_NT 64
__global__ __launch_bounds__(256) void k3_gemm(const uint16_t* __restrict__ Abf,
                                               const uint16_t* __restrict__ Bbf,
                                               const float* __restrict__ invA,
                                               uint16_t* __restrict__ Cbf) {
    __shared__ __align__(16) uint16_t As[2][128 * 64];   // 2 x 16 KiB
    __shared__ __align__(16) uint16_t Bs[2][128 * 64];   // 2 x 16 KiB
    const int t = threadIdx.x;
    const int lane = t & 63;
    const int wid = t >> 6;
    const int wr = wid >> 1;
    const int wc = wid & 1;

    const int bid = blockIdx.x;
    const int wgid = (bid & 7) * 64 + (bid >> 3);
    const int bm = (wgid >> 4) * 128;
    const int bn = (wgid & 15) * 128;

    const uint16_t* asrc[4];
    const uint16_t* bsrc[4];
    int cdst[4];
#pragma unroll
    for (int i = 0; i < 4; ++i) {
        const int c = t + i * 256;
        const int row = c >> 3, ch = c & 7;
        asrc[i] = Abf + (size_t)(bm + row) * GK + ((ch ^ (row & 7)) << 3);
        bsrc[i] = Bbf + (size_t)(bn + row) * GK + ((ch ^ (row & 7)) << 3);
        cdst[i] = c << 3;
    }

    int offA[4][2], offB[4][2];
#pragma unroll
    for (int f = 0; f < 4; ++f)
#pragma unroll
        for (int ks = 0; ks < 2; ++ks) {
            const int ra = wr * 64 + f * 16 + (lane & 15);
            offA[f][ks] = ra * 64 + (((ks * 4 + (lane >> 4)) ^ (ra & 7)) << 3);
            const int rb = wc * 64 + f * 16 + (lane & 15);
            offB[f][ks] = rb * 64 + (((ks * 4 + (lane >> 4)) ^ (rb & 7)) << 3);
        }

    f32x4 acc[4][4];
#pragma unroll
    for (int i = 0; i < 4; ++i)
#pragma unroll
        for (int j = 0; j < 4; ++j) acc[i][j] = (f32x4){0.f, 0.f, 0.f, 0.f};

#define K3_STAGE(buf, kt)                                  \
    do {                                                   \
        const size_t ko_ = (size_t)(kt) * 64;              \
        GLL(asrc[0] + ko_, &As[buf][cdst[0]]);             \
        GLL(asrc[1] + ko_, &As[buf][cdst[1]]);             \
        GLL(asrc[2] + ko_, &As[buf][cdst[2]]);             \
        GLL(asrc[3] + ko_, &As[buf][cdst[3]]);             \
        GLL(bsrc[0] + ko_, &Bs[buf][cdst[0]]);             \
        GLL(bsrc[1] + ko_, &Bs[buf][cdst[1]]);             \
        GLL(bsrc[2] + ko_, &Bs[buf][cdst[2]]);             \
        GLL(bsrc[3] + ko_, &Bs[buf][cdst[3]]);             \
    } while (0)

    K3_STAGE(0, 0);
    __syncthreads();

    for (int kt = 0; kt < K3_NT; ++kt) {
        const int cur = kt & 1;
        if (kt < K3_NT - 1) K3_STAGE(cur ^ 1, kt + 1);

        const uint16_t* Ab = As[cur];
        const uint16_t* Bb = Bs[cur];
        bf16x8 af[4][2], bfr[4][2];
#pragma unroll
        for (int ks = 0; ks < 2; ++ks) {
#pragma unroll
            for (int f = 0; f < 4; ++f) af[f][ks] = *(const bf16x8*)(Ab + offA[f][ks]);
#pragma unroll
            for (int j = 0; j < 4; ++j) bfr[j][ks] = *(const bf16x8*)(Bb + offB[j][ks]);
        }
        __builtin_amdgcn_s_setprio(1);
#pragma unroll
        for (int ks = 0; ks < 2; ++ks)
#pragma unroll
            for (int f = 0; f < 4; ++f)
#pragma unroll
                for (int j = 0; j < 4; ++j)
                    acc[f][j] = __builtin_amdgcn_mfma_f32_16x16x32_bf16(af[f][ks], bfr[j][ks], acc[f][j], 0, 0, 0);
        __builtin_amdgcn_s_setprio(0);
        __syncthreads();
    }
#undef K3_STAGE

#pragma unroll
    for (int f = 0; f < 4; ++f) {
        float invv[4];
#pragma unroll
        for (int r = 0; r < 4; ++r)
            invv[r] = invA[bm + wr * 64 + f * 16 + (lane >> 4) * 4 + r];
#pragma unroll
        for (int j = 0; j < 4; ++j)
#pragma unroll
            for (int r = 0; r < 4; ++r) {
                const int row = bm + wr * 64 + f * 16 + (lane >> 4) * 4 + r;
                const int col = bn + wc * 64 + j * 16 + (lane & 15);
                Cbf[(size_t)row * GN + col] = f2bf(acc[f][j][r] * invv[r]);
            }
    }
}

// ---------------------------------------------------------------------------
// K6: one wave per node n.  Wt register-double-buffered (R5).
// R6: folds the pscale reduction — lane l sums 8 partials of node n
// (loads issued at kernel start, hidden under MFMA work), shfl_xor reduce
// just before epilogue replaces the scale[] read.  No atomics anywhere.
// ---------------------------------------------------------------------------
__global__ __launch_bounds__(256) void k6_gconv(const float* __restrict__ x,
                                                const uint16_t* __restrict__ XG,
                                                const uint16_t* __restrict__ Wt,
                                                const float* __restrict__ biasn,
                                                const float* __restrict__ pscale,
                                                const float* __restrict__ lin_w,
                                                const float* __restrict__ lin_b,
                                                float* __restrict__ out) {
    __shared__ __align__(16) uint16_t Lws[64][72];
    const int t = threadIdx.x;
    const int n0 = blockIdx.x * 4;
    const int w = t >> 6, lane = t & 63;
    const int n = n0 + w;

    // scale partial loads first: 8 independent loads, consumed in epilogue
    float psum = 0.f;
#pragma unroll
    for (int k = 0; k < 8; ++k)
        psum += pscale[(size_t)(k * 64 + lane) * 4096 + n];

    {
        const int o = t >> 2, i0 = (t & 3) * 16;
        const float4* lp = (const float4*)(lin_w + o * 64 + i0);
        float4 a0 = lp[0], a1 = lp[1], a2 = lp[2], a3 = lp[3];
        union { uint16_t u[16]; uint4 v[2]; } r;
        r.u[0] = f2bf(a0.x); r.u[1] = f2bf(a0.y); r.u[2]  = f2bf(a0.z); r.u[3]  = f2bf(a0.w);
        r.u[4] = f2bf(a1.x); r.u[5] = f2bf(a1.y); r.u[6]  = f2bf(a1.z); r.u[7]  = f2bf(a1.w);
        r.u[8] = f2bf(a2.x); r.u[9] = f2bf(a2.y); r.u[10] = f2bf(a2.z); r.u[11] = f2bf(a2.w);
        r.u[12] = f2bf(a3.x); r.u[13] = f2bf(a3.y); r.u[14] = f2bf(a3.z); r.u[15] = f2bf(a3.w);
        *(uint4*)&Lws[o][i0] = r.v[0];
        *(uint4*)&Lws[o][i0 + 8] = r.v[1];
    }

    const int l15 = lane & 15;
    const int q8 = (lane >> 4) * 8;

    bf16x8 a[2][4];
#pragma unroll
    for (int mt = 0; mt < 2; ++mt) {
        const int b = mt * 16 + l15;
        const float* xp = x + ((size_t)b * Ndim + n) * 64 + q8;
        a[mt][0] = pack8(((const float4*)xp)[0], ((const float4*)xp)[1]);
        a[mt][1] = pack8(((const float4*)(xp + 32))[0], ((const float4*)(xp + 32))[1]);
        const uint16_t* gp = XG + (size_t)n * 2048 + b * 64 + q8;
        a[mt][2] = *(const bf16x8*)gp;
        a[mt][3] = *(const bf16x8*)(gp + 32);
    }

    f32x4 accg[2][4], accs[2][4];
#pragma unroll
    for (int mt = 0; mt < 2; ++mt)
#pragma unroll
        for (int j = 0; j < 4; ++j) {
            accg[mt][j] = (f32x4){0.f, 0.f, 0.f, 0.f};
            accs[mt][j] = (f32x4){0.f, 0.f, 0.f, 0.f};
        }

    const uint16_t* wp = Wt + (size_t)n * 8192 + l15 * 128 + q8;

    bf16x8 bw0[4], bw1[4];
#pragma unroll
    for (int j = 0; j < 4; ++j) bw0[j] = *(const bf16x8*)(wp + j * 2048);

    __syncthreads();   // Lws ready

    // ---- ks = 0 ----
#pragma unroll
    for (int j = 0; j < 4; ++j) bw1[j] = *(const bf16x8*)(wp + j * 2048 + 32);
#pragma unroll
    for (int mt = 0; mt < 2; ++mt)
#pragma unroll
        for (int j = 0; j < 4; ++j)
            accg[mt][j] = __builtin_amdgcn_mfma_f32_16x16x32_bf16(a[mt][0], bw0[j], accg[mt][j], 0, 0, 0);
    {
        bf16x8 bl[4];
#pragma unroll
        for (int j = 0; j < 4; ++j) bl[j] = *(const bf16x8*)&Lws[j * 16 + l15][q8];
#pragma unroll
        for (int mt = 0; mt < 2; ++mt)
#pragma unroll
            for (int j = 0; j < 4; ++j)
                accs[mt][j] = __builtin_amdgcn_mfma_f32_16x16x32_bf16(a[mt][0], bl[j], accs[mt][j], 0, 0, 0);
    }
    // ---- ks = 1 ----
#pragma unroll
    for (int j = 0; j < 4; ++j) bw0[j] = *(const bf16x8*)(wp + j * 2048 + 64);
#pragma unroll
    for (int mt = 0; mt < 2; ++mt)
#pragma unroll
        for (int j = 0; j < 4; ++j)
            accg[mt][j] = __builtin_amdgcn_mfma_f32_16x16x32_bf16(a[mt][1], bw1[j], accg[mt][j], 0, 0, 0);
    {
        bf16x8 bl[4];
#pragma unroll
        for (int j = 0; j < 4; ++j) bl[j] = *(const bf16x8*)&Lws[j * 16 + l15][32 + q8];
#pragma unroll
        for (int mt = 0; mt < 2; ++mt)
#pragma unroll
            for (int j = 0; j < 4; ++j)
                accs[mt][j] = __builtin_amdgcn_mfma_f32_16x16x32_bf16(a[mt][1], bl[j], accs[mt][j], 0, 0, 0);
    }
    // ---- ks = 2 ----
#pragma unroll
    for (int j = 0; j < 4; ++j) bw1[j] = *(const bf16x8*)(wp + j * 2048 + 96);
#pragma unroll
    for (int mt = 0; mt < 2; ++mt)
#pragma unroll
        for (int j = 0; j < 4; ++j)
            accg[mt][j] = __builtin_amdgcn_mfma_f32_16x16x32_bf16(a[mt][2], bw0[j], accg[mt][j], 0, 0, 0);
    // ---- ks = 3 ----
#pragma unroll
    for (int mt = 0; mt < 2; ++mt)
#pragma unroll
        for (int j = 0; j < 4; ++j)
            accg[mt][j] = __builtin_amdgcn_mfma_f32_16x16x32_bf16(a[mt][3], bw1[j], accg[mt][j], 0, 0, 0);

    // finish scale reduction: all 64 lanes end with sum over 512 partials
#pragma unroll
    for (int off = 32; off > 0; off >>= 1) psum += __shfl_xor(psum, off, 64);
    const float sc = psum;

#pragma unroll
    for (int j = 0; j < 4; ++j) {
        const int o = j * 16 + l15;
        const float bn = biasn[(size_t)n * 64 + o];
        const float lb = lin_b[o];
#pragma unroll
        for (int mt = 0; mt < 2; ++mt)
#pragma unroll
            for (int r = 0; r < 4; ++r) {
                const int b = mt * 16 + (lane >> 4) * 4 + r;
                const float gg = accg[mt][j][r] + bn;
                const float xs = sc * accs[mt][j][r] + lb;
                out[((size_t)b * Ndim + n) * 64 + o] = gg + xs / (1.f + __expf(-xs));
            }
    }
}

// ---------------------------------------------------------------------------
extern "C" void kernel_launch(void* const* d_in, const int* in_sizes, int n_in,
                              void* d_out, int out_size, void* d_ws, size_t ws_size,
                              hipStream_t stream) {
    const float* x         = (const float*)d_in[0];
    const float* E         = (const float*)d_in[1];
    const float* pool      = (const float*)d_in[2];
    const float* bias_pool = (const float*)d_in[3];
    const float* lin_w     = (const float*)d_in[4];
    const float* lin_b     = (const float*)d_in[5];
    const float* adj       = (const float*)d_in[6];
    float* out = (float*)d_out;

    uint8_t* ws = (uint8_t*)d_ws;
    uint16_t* A      = (uint16_t*)(ws);                 // 4096*4096*2  = 32 MiB
    uint16_t* Xtt    = (uint16_t*)(ws + 33554432);      // 2048*4096*2  = 16 MiB
    uint16_t* XG     = (uint16_t*)(ws + 50331648);      // 4096*2048*2  = 16 MiB
    uint16_t* Wt     = (uint16_t*)(ws + 67108864);      // 4096*8192*2  = 64 MiB
    float*    biasn  = (float*)   (ws + 134217728);     // 4096*64*4    = 1 MiB
    float*    sd     = (float*)   (ws + 135266304);     // 16 KiB
    float*    poolT  = (float*)   (ws + 135299072);     // 512 KiB
    float*    invA   = (float*)   (ws + 135823360);     // 16 KiB
    float*    rs4    = (float*)   (ws + 135839744);     // 64 KiB
    float*    pscale = (float*)   (ws + 135905280);     // 512*4096*4 = 8 MiB

    p1_prep<<<dim3(7232), dim3(256), 0, stream>>>(E, x, adj, pool, A, rs4, Xtt, sd, poolT);
    p2_mid<<<dim3(1552), dim3(256), 0, stream>>>(E, adj, sd, poolT, bias_pool, pscale, Wt, biasn, rs4, invA);
    k3_gemm<<<dim3(512), dim3(256), 0, stream>>>(A, Xtt, invA, XG);
    k6_gconv<<<dim3(1024), dim3(256), 0, stream>>>(x, XG, Wt, biasn, pscale, lin_w, lin_b, out);
}

// Round 7
// 326.904 us; speedup vs baseline: 1.1653x; 1.1653x over previous
//
#include <hip/hip_runtime.h>
#include <stdint.h>

// Problem dims
#define Bdim 32
#define Ndim 4096
#define Cin  64
#define Cout 64
#define Demb 16

typedef __bf16 bf16x8 __attribute__((ext_vector_type(8)));
typedef float  f32x4  __attribute__((ext_vector_type(4)));

#define GLOBAL_AS(p) ((__attribute__((address_space(1))) void*)(p))
#define LDS_AS(p)    ((__attribute__((address_space(3))) void*)(p))
#define GLL(gp, lp)  __builtin_amdgcn_global_load_lds(GLOBAL_AS(gp), LDS_AS(lp), 16, 0, 0)

__device__ __forceinline__ uint16_t f2bf(float x) {
    union { float f; uint32_t u; } v; v.f = x;
    uint32_t r = v.u + 0x7FFFu + ((v.u >> 16) & 1u);   // RNE, finite inputs
    return (uint16_t)(r >> 16);
}

__device__ __forceinline__ bf16x8 pack8(float4 a, float4 b) {
    union { uint16_t u[8]; bf16x8 v; } r;
    r.u[0] = f2bf(a.x); r.u[1] = f2bf(a.y); r.u[2] = f2bf(a.z); r.u[3] = f2bf(a.w);
    r.u[4] = f2bf(b.x); r.u[5] = f2bf(b.y); r.u[6] = f2bf(b.z); r.u[7] = f2bf(b.w);
    return r.v;
}

// ---------------------------------------------------------------------------
// P1: fused independent prep (blockIdx-partitioned roles, all 256-thread):
//   [0,1024)     k1: A~[n][m] = bf16(exp(relu(E[n]·E[m]))) UNNORMALIZED.
//                    4-way column-split; partial rowsums -> rs4[n][chunk]
//   [1024,3072)  k2: Xtt[b*64+c][m] = bf16(x[b][m][c])  (LDS tile transpose)
//   [3072,7168)  k4a: sd[n] = rsqrt(rowsum(adj[n]) + 0.5)
//   [7168,7232)  k5a: poolT[d][o*128+ki] = pool[d][ki*64+o]
// ---------------------------------------------------------------------------
__global__ __launch_bounds__(256) void p1_prep(const float* __restrict__ E,
                                               const float* __restrict__ x,
                                               const float* __restrict__ adj,
                                               const float* __restrict__ pool,
                                               uint16_t* __restrict__ A,
                                               float* __restrict__ rs4,
                                               uint16_t* __restrict__ Xtt,
                                               float* __restrict__ sd,
                                               float* __restrict__ poolT) {
    __shared__ __align__(16) uint8_t smem[9232];
    const int t = threadIdx.x;
    const int blk = blockIdx.x;

    if (blk < 1024) {
        // ---- k1: dynamic adjacency, 16 rows x 1024 cols per block ----
        float* Er_s = (float*)smem;            // 16x16
        float* red_s = (float*)(smem + 1024);  // 4
        const int n0 = (blk >> 2) * 16;
        const int chunk = blk & 3;
        const int m0 = chunk * 1024;
        Er_s[t] = E[n0 * Demb + t];
        __syncthreads();
        for (int half = 0; half < 2; ++half) {
            float er[8][16];
#pragma unroll
            for (int r = 0; r < 8; ++r)
#pragma unroll
                for (int d = 0; d < 16; ++d) er[r][d] = Er_s[(half * 8 + r) * 16 + d];
            float sacc[8];
#pragma unroll
            for (int r = 0; r < 8; ++r) sacc[r] = 0.f;
            for (int c = 0; c < 4; ++c) {
                const int m = m0 + c * 256 + t;
                const float4* ep = (const float4*)(E + (size_t)m * Demb);
                float4 e0 = ep[0], e1 = ep[1], e2 = ep[2], e3 = ep[3];
                float em[16] = {e0.x, e0.y, e0.z, e0.w, e1.x, e1.y, e1.z, e1.w,
                                e2.x, e2.y, e2.z, e2.w, e3.x, e3.y, e3.z, e3.w};
#pragma unroll
                for (int r = 0; r < 8; ++r) {
                    float v = 0.f;
#pragma unroll
                    for (int d = 0; d < 16; ++d) v = fmaf(er[r][d], em[d], v);
                    v = fmaxf(v, 0.f);
                    const float e = __expf(v);
                    sacc[r] += e;
                    A[(size_t)(n0 + half * 8 + r) * Ndim + m] = f2bf(e);
                }
            }
#pragma unroll
            for (int r = 0; r < 8; ++r) {
                float s = sacc[r];
#pragma unroll
                for (int off = 32; off > 0; off >>= 1) s += __shfl_down(s, off, 64);
                __syncthreads();
                if ((t & 63) == 0) red_s[t >> 6] = s;
                __syncthreads();
                if (t == 0)
                    rs4[(size_t)(n0 + half * 8 + r) * 4 + chunk] =
                        red_s[0] + red_s[1] + red_s[2] + red_s[3];
            }
            __syncthreads();
        }
    } else if (blk < 3072) {
        // ---- k2: x transpose to Xtt ----
        auto T = (uint16_t(*)[72])smem;
        const int idx = blk - 1024;
        const int m0 = (idx & 63) * 64;
        const int b = idx >> 6;
        const int c = t & 63;
#pragma unroll
        for (int j = 0; j < 16; ++j) {
            const int m = (t >> 6) + j * 4;
            T[c][m] = f2bf(x[((size_t)b * Ndim + (m0 + m)) * Cin + c]);
        }
        __syncthreads();
        const int c2 = t >> 2, mo = (t & 3) * 16;
        const uint4* src = (const uint4*)&T[c2][mo];
        uint4 v0 = src[0], v1 = src[1];
        uint4* dst = (uint4*)(Xtt + (size_t)(b * Cin + c2) * Ndim + m0 + mo);
        dst[0] = v0;
        dst[1] = v1;
    } else if (blk < 7168) {
        // ---- k4a: adj rowsum -> sd ----
        float* red_s = (float*)smem;
        const int n = blk - 3072;
        const float4* ap = (const float4*)(adj + (size_t)n * Ndim);
        float s = 0.f;
#pragma unroll
        for (int q = 0; q < 4; ++q) {
            float4 a = ap[q * 256 + t];
            s += a.x + a.y + a.z + a.w;
        }
#pragma unroll
        for (int off = 32; off > 0; off >>= 1) s += __shfl_down(s, off, 64);
        if ((t & 63) == 0) red_s[t >> 6] = s;
        __syncthreads();
        if (t == 0) sd[n] = sqrtf(1.f / (red_s[0] + red_s[1] + red_s[2] + red_s[3] + 0.5f));
    } else {
        // ---- k5a: pool transpose ----
        const int idx = blk - 7168;
        const int d = idx >> 2;
        const int base = (idx & 3) * 2048;
#pragma unroll
        for (int j = 0; j < 8; ++j) {
            const int e = base + j * 256 + t;          // e = ki*64 + o
            const float v = pool[d * 8192 + e];
            poolT[d * 8192 + (e & 63) * 128 + (e >> 6)] = v;
        }
    }
}

// ---------------------------------------------------------------------------
// P2: k4b + k5b + invA finalize.
//   [0,512)      k4b: partial colsum(rowsoftmax(rowsoftmax(sym-norm adj)))
//                R7 DE-SPILL: R5/R6's wave-owned rows kept e1[64]+sdm[64]+
//                colsum[64] = 192 floats live at VGPR_Count=140 -> ~50 floats
//                spilled to scratch, round-tripped 3x per row = the 106 us
//                (MfmaUtil 0 / VALU 18% / Occ 10% = all pipes idle, latency).
//                Now: block owns a row, 16 cols/thread -> 48 floats state,
//                static indexing, zero spill.  Same pscale output layout.
//   [512,1536)   k5b: Wt[n][o*128+ki] = bf16(sum_d E[n,d]*poolT[d][...]); biasn
//   [1536,1552)  invA[n] = 1/sum(rs4[n][0..3])
// ---------------------------------------------------------------------------
__global__ __launch_bounds__(256) void p2_mid(const float* __restrict__ E,
                                              const float* __restrict__ adj,
                                              const float* __restrict__ sd,
                                              const float* __restrict__ poolT,
                                              const float* __restrict__ bias_pool,
                                              float* __restrict__ pscale,
                                              uint16_t* __restrict__ Wt,
                                              float* __restrict__ biasn,
                                              const float* __restrict__ rs4,
                                              float* __restrict__ invA) {
    __shared__ __align__(16) uint8_t smem[16384];
    const int t = threadIdx.x;
    const int blk = blockIdx.x;

    if (blk < 512) {
        // ---- k4b (block-owned rows, 16 cols/thread, no spill) ----
        float* red = (float*)smem;            // red[0..3]=s1 slots, [4..7]=s2
        const int w64 = t >> 6, lane = t & 63;
        const int nb = blk * 8;
        const int cbase = t * 4;              // col = u*1024 + cbase + j

        float sdm[4][4];
#pragma unroll
        for (int u = 0; u < 4; ++u) {
            float4 s4 = *(const float4*)(sd + u * 1024 + cbase);
            sdm[u][0] = s4.x; sdm[u][1] = s4.y; sdm[u][2] = s4.z; sdm[u][3] = s4.w;
        }
        float colacc[4][4];
#pragma unroll
        for (int u = 0; u < 4; ++u)
#pragma unroll
            for (int j = 0; j < 4; ++j) colacc[u][j] = 0.f;

        for (int r = 0; r < 8; ++r) {
            const int n = nb + r;
            const float sdn = sd[n];
            float e1[4][4];
            float s1 = 0.f;
#pragma unroll
            for (int u = 0; u < 4; ++u) {
                float4 a4 = *(const float4*)(adj + (size_t)n * Ndim + u * 1024 + cbase);
                float vv[4] = {a4.x, a4.y, a4.z, a4.w};
#pragma unroll
                for (int j = 0; j < 4; ++j) {
                    const float vd = vv[j] + ((u * 1024 + cbase + j) == n ? 0.5f : 0.f);
                    const float e = __expf(sdn * vd * sdm[u][j]);
                    e1[u][j] = e;
                    s1 += e;
                }
            }
            // block reduce s1 (slot 0; one barrier — slots alternate so the
            // next write to this slot is separated by the s2 barrier)
#pragma unroll
            for (int off = 32; off > 0; off >>= 1) s1 += __shfl_xor(s1, off, 64);
            if (lane == 0) red[w64] = s1;
            __syncthreads();
            const float inv1 = 1.f / (red[0] + red[1] + red[2] + red[3]);

            float s2 = 0.f;
#pragma unroll
            for (int u = 0; u < 4; ++u)
#pragma unroll
                for (int j = 0; j < 4; ++j) {
                    const float e = __expf(e1[u][j] * inv1);
                    e1[u][j] = e;
                    s2 += e;
                }
#pragma unroll
            for (int off = 32; off > 0; off >>= 1) s2 += __shfl_xor(s2, off, 64);
            if (lane == 0) red[4 + w64] = s2;
            __syncthreads();
            const float inv2 = 1.f / (red[4] + red[5] + red[6] + red[7]);
#pragma unroll
            for (int u = 0; u < 4; ++u)
#pragma unroll
                for (int j = 0; j < 4; ++j)
                    colacc[u][j] = fmaf(e1[u][j], inv2, colacc[u][j]);
        }
        // one coalesced float4 store pass of this block's partial colsums
#pragma unroll
        for (int u = 0; u < 4; ++u) {
            float4 o = {colacc[u][0], colacc[u][1], colacc[u][2], colacc[u][3]};
            *(float4*)(pscale + (size_t)blk * 4096 + u * 1024 + cbase) = o;
        }
    } else if (blk < 1536) {
        // ---- k5b ----
        float* En = (float*)smem;   // 32x16
        const int idx = blk - 512;
        const int ec = idx & 7;
        const int n0 = (idx >> 3) * 32;
        En[t] = E[n0 * Demb + t];
        En[t + 256] = E[n0 * Demb + t + 256];
        __syncthreads();

        const int e0 = ec * 1024 + t * 4;
        float4 P[16];
#pragma unroll
        for (int d = 0; d < 16; ++d) P[d] = *(const float4*)(poolT + d * 8192 + e0);

        for (int g = 0; g < 32; ++g) {
            float4 acc = {0.f, 0.f, 0.f, 0.f};
#pragma unroll
            for (int d = 0; d < 16; ++d) {
                const float e = En[g * 16 + d];
                acc.x = fmaf(e, P[d].x, acc.x);
                acc.y = fmaf(e, P[d].y, acc.y);
                acc.z = fmaf(e, P[d].z, acc.z);
                acc.w = fmaf(e, P[d].w, acc.w);
            }
            union { uint16_t u[4]; uint2 v; } r;
            r.u[0] = f2bf(acc.x); r.u[1] = f2bf(acc.y);
            r.u[2] = f2bf(acc.z); r.u[3] = f2bf(acc.w);
            *(uint2*)(Wt + (size_t)(n0 + g) * 8192 + e0) = r.v;
        }

        if (ec == 0) {
            const int o = t & 63, gq = t >> 6;
#pragma unroll
            for (int gi = 0; gi < 8; ++gi) {
                const int g = gi * 4 + gq;
                float a = 0.f;
#pragma unroll
                for (int d = 0; d < 16; ++d) a = fmaf(En[g * 16 + d], bias_pool[d * 64 + o], a);
                biasn[(size_t)(n0 + g) * 64 + o] = a;
            }
        }
    } else {
        // ---- invA finalize ----
        const int n = (blk - 1536) * 256 + t;
        const float4 v = *(const float4*)(rs4 + (size_t)n * 4);
        invA[n] = 1.f / (v.x + v.y + v.z + v.w);
    }
}

// ---------------------------------------------------------------------------
// K3 (R4-proven, frozen): XG[n][j] = invA[n] * sum_m A~[n][m] * Xtt[j][m]
// 128x128 tile, BK=64, dbuf, one __syncthreads per tile, XOR chunk swizzle,
// XCD-bijective block swizzle.  88.9 us / MfmaUtil 32% measured (R4).
// ---------------------------------------------------------------------------
#define GK 4096
#define GN 2048
#define K3_NT 64
__global__ __launch_bounds__(256) void k3_gemm(const uint16_t* __restrict__ Abf,
                                               const uint16_t* __restrict__ Bbf,
                                               const float* __restrict__ invA,
                                               uint16_t* __restrict__ Cbf) {
    __shared__ __align__(16) uint16_t As[2][128 * 64];   // 2 x 16 KiB
    __shared__ __align__(16) uint16_t Bs[2][128 * 64];   // 2 x 16 KiB
    const int t = threadIdx.x;
    const int lane = t & 63;
    const int wid = t >> 6;
    const int wr = wid >> 1;
    const int wc = wid & 1;

    const int bid = blockIdx.x;
    const int wgid = (bid & 7) * 64 + (bid >> 3);
    const int bm = (wgid >> 4) * 128;
    const int bn = (wgid & 15) * 128;

    const uint16_t* asrc[4];
    const uint16_t* bsrc[4];
    int cdst[4];
#pragma unroll
    for (int i = 0; i < 4; ++i) {
        const int c = t + i * 256;
        const int row = c >> 3, ch = c & 7;
        asrc[i] = Abf + (size_t)(bm + row) * GK + ((ch ^ (row & 7)) << 3);
        bsrc[i] = Bbf + (size_t)(bn + row) * GK + ((ch ^ (row & 7)) << 3);
        cdst[i] = c << 3;
    }

    int offA[4][2], offB[4][2];
#pragma unroll
    for (int f = 0; f < 4; ++f)
#pragma unroll
        for (int ks = 0; ks < 2; ++ks) {
            const int ra = wr * 64 + f * 16 + (lane & 15);
            offA[f][ks] = ra * 64 + (((ks * 4 + (lane >> 4)) ^ (ra & 7)) << 3);
            const int rb = wc * 64 + f * 16 + (lane & 15);
            offB[f][ks] = rb * 64 + (((ks * 4 + (lane >> 4)) ^ (rb & 7)) << 3);
        }

    f32x4 acc[4][4];
#pragma unroll
    for (int i = 0; i < 4; ++i)
#pragma unroll
        for (int j = 0; j < 4; ++j) acc[i][j] = (f32x4){0.f, 0.f, 0.f, 0.f};

#define K3_STAGE(buf, kt)                                  \
    do {                                                   \
        const size_t ko_ = (size_t)(kt) * 64;              \
        GLL(asrc[0] + ko_, &As[buf][cdst[0]]);             \
        GLL(asrc[1] + ko_, &As[buf][cdst[1]]);             \
        GLL(asrc[2] + ko_, &As[buf][cdst[2]]);             \
        GLL(asrc[3] + ko_, &As[buf][cdst[3]]);             \
        GLL(bsrc[0] + ko_, &Bs[buf][cdst[0]]);             \
        GLL(bsrc[1] + ko_, &Bs[buf][cdst[1]]);             \
        GLL(bsrc[2] + ko_, &Bs[buf][cdst[2]]);             \
        GLL(bsrc[3] + ko_, &Bs[buf][cdst[3]]);             \
    } while (0)

    K3_STAGE(0, 0);
    __syncthreads();

    for (int kt = 0; kt < K3_NT; ++kt) {
        const int cur = kt & 1;
        if (kt < K3_NT - 1) K3_STAGE(cur ^ 1, kt + 1);

        const uint16_t* Ab = As[cur];
        const uint16_t* Bb = Bs[cur];
        bf16x8 af[4][2], bfr[4][2];
#pragma unroll
        for (int ks = 0; ks < 2; ++ks) {
#pragma unroll
            for (int f = 0; f < 4; ++f) af[f][ks] = *(const bf16x8*)(Ab + offA[f][ks]);
#pragma unroll
            for (int j = 0; j < 4; ++j) bfr[j][ks] = *(const bf16x8*)(Bb + offB[j][ks]);
        }
        __builtin_amdgcn_s_setprio(1);
#pragma unroll
        for (int ks = 0; ks < 2; ++ks)
#pragma unroll
            for (int f = 0; f < 4; ++f)
#pragma unroll
                for (int j = 0; j < 4; ++j)
                    acc[f][j] = __builtin_amdgcn_mfma_f32_16x16x32_bf16(af[f][ks], bfr[j][ks], acc[f][j], 0, 0, 0);
        __builtin_amdgcn_s_setprio(0);
        __syncthreads();
    }
#undef K3_STAGE

#pragma unroll
    for (int f = 0; f < 4; ++f) {
        float invv[4];
#pragma unroll
        for (int r = 0; r < 4; ++r)
            invv[r] = invA[bm + wr * 64 + f * 16 + (lane >> 4) * 4 + r];
#pragma unroll
        for (int j = 0; j < 4; ++j)
#pragma unroll
            for (int r = 0; r < 4; ++r) {
                const int row = bm + wr * 64 + f * 16 + (lane >> 4) * 4 + r;
                const int col = bn + wc * 64 + j * 16 + (lane & 15);
                Cbf[(size_t)row * GN + col] = f2bf(acc[f][j][r] * invv[r]);
            }
    }
}

// ---------------------------------------------------------------------------
// K6: one wave per node n.  Wt register-double-buffered (R5).
// pscale fold (R6): lane l sums 8 partials at kernel start, shfl_xor reduce
// before epilogue.  No atomics anywhere.
// ---------------------------------------------------------------------------
__global__ __launch_bounds__(256) void k6_gconv(const float* __restrict__ x,
                                                const uint16_t* __restrict__ XG,
                                                const uint16_t* __restrict__ Wt,
                                                const float* __restrict__ biasn,
                                                const float* __restrict__ pscale,
                                                const float* __restrict__ lin_w,
                                                const float* __restrict__ lin_b,
                                                float* __restrict__ out) {
    __shared__ __align__(16) uint16_t Lws[64][72];
    const int t = threadIdx.x;
    const int n0 = blockIdx.x * 4;
    const int w = t >> 6, lane = t & 63;
    const int n = n0 + w;

    // scale partial loads first: 8 independent loads, consumed in epilogue
    float psum = 0.f;
#pragma unroll
    for (int k = 0; k < 8; ++k)
        psum += pscale[(size_t)(k * 64 + lane) * 4096 + n];

    {
        const int o = t >> 2, i0 = (t & 3) * 16;
        const float4* lp = (const float4*)(lin_w + o * 64 + i0);
        float4 a0 = lp[0], a1 = lp[1], a2 = lp[2], a3 = lp[3];
        union { uint16_t u[16]; uint4 v[2]; } r;
        r.u[0] = f2bf(a0.x); r.u[1] = f2bf(a0.y); r.u[2]  = f2bf(a0.z); r.u[3]  = f2bf(a0.w);
        r.u[4] = f2bf(a1.x); r.u[5] = f2bf(a1.y); r.u[6]  = f2bf(a1.z); r.u[7]  = f2bf(a1.w);
        r.u[8] = f2bf(a2.x); r.u[9] = f2bf(a2.y); r.u[10] = f2bf(a2.z); r.u[11] = f2bf(a2.w);
        r.u[12] = f2bf(a3.x); r.u[13] = f2bf(a3.y); r.u[14] = f2bf(a3.z); r.u[15] = f2bf(a3.w);
        *(uint4*)&Lws[o][i0] = r.v[0];
        *(uint4*)&Lws[o][i0 + 8] = r.v[1];
    }

    const int l15 = lane & 15;
    const int q8 = (lane >> 4) * 8;

    bf16x8 a[2][4];
#pragma unroll
    for (int mt = 0; mt < 2; ++mt) {
        const int b = mt * 16 + l15;
        const float* xp = x + ((size_t)b * Ndim + n) * 64 + q8;
        a[mt][0] = pack8(((const float4*)xp)[0], ((const float4*)xp)[1]);
        a[mt][1] = pack8(((const float4*)(xp + 32))[0], ((const float4*)(xp + 32))[1]);
        const uint16_t* gp = XG + (size_t)n * 2048 + b * 64 + q8;
        a[mt][2] = *(const bf16x8*)gp;
        a[mt][3] = *(const bf16x8*)(gp + 32);
    }

    f32x4 accg[2][4], accs[2][4];
#pragma unroll
    for (int mt = 0; mt < 2; ++mt)
#pragma unroll
        for (int j = 0; j < 4; ++j) {
            accg[mt][j] = (f32x4){0.f, 0.f, 0.f, 0.f};
            accs[mt][j] = (f32x4){0.f, 0.f, 0.f, 0.f};
        }

    const uint16_t* wp = Wt + (size_t)n * 8192 + l15 * 128 + q8;

    bf16x8 bw0[4], bw1[4];
#pragma unroll
    for (int j = 0; j < 4; ++j) bw0[j] = *(const bf16x8*)(wp + j * 2048);

    __syncthreads();   // Lws ready

    // ---- ks = 0 ----
#pragma unroll
    for (int j = 0; j < 4; ++j) bw1[j] = *(const bf16x8*)(wp + j * 2048 + 32);
#pragma unroll
    for (int mt = 0; mt < 2; ++mt)
#pragma unroll
        for (int j = 0; j < 4; ++j)
            accg[mt][j] = __builtin_amdgcn_mfma_f32_16x16x32_bf16(a[mt][0], bw0[j], accg[mt][j], 0, 0, 0);
    {
        bf16x8 bl[4];
#pragma unroll
        for (int j = 0; j < 4; ++j) bl[j] = *(const bf16x8*)&Lws[j * 16 + l15][q8];
#pragma unroll
        for (int mt = 0; mt < 2; ++mt)
#pragma unroll
            for (int j = 0; j < 4; ++j)
                accs[mt][j] = __builtin_amdgcn_mfma_f32_16x16x32_bf16(a[mt][0], bl[j], accs[mt][j], 0, 0, 0);
    }
    // ---- ks = 1 ----
#pragma unroll
    for (int j = 0; j < 4; ++j) bw0[j] = *(const bf16x8*)(wp + j * 2048 + 64);
#pragma unroll
    for (int mt = 0; mt < 2; ++mt)
#pragma unroll
        for (int j = 0; j < 4; ++j)
            accg[mt][j] = __builtin_amdgcn_mfma_f32_16x16x32_bf16(a[mt][1], bw1[j], accg[mt][j], 0, 0, 0);
    {
        bf16x8 bl[4];
#pragma unroll
        for (int j = 0; j < 4; ++j) bl[j] = *(const bf16x8*)&Lws[j * 16 + l15][32 + q8];
#pragma unroll
        for (int mt = 0; mt < 2; ++mt)
#pragma unroll
            for (int j = 0; j < 4; ++j)
                accs[mt][j] = __builtin_amdgcn_mfma_f32_16x16x32_bf16(a[mt][1], bl[j], accs[mt][j], 0, 0, 0);
    }
    // ---- ks = 2 ----
#pragma unroll
    for (int j = 0; j < 4; ++j) bw1[j] = *(const bf16x8*)(wp + j * 2048 + 96);
#pragma unroll
    for (int mt = 0; mt < 2; ++mt)
#pragma unroll
        for (int j = 0; j < 4; ++j)
            accg[mt][j] = __builtin_amdgcn_mfma_f32_16x16x32_bf16(a[mt][2], bw0[j], accg[mt][j], 0, 0, 0);
    // ---- ks = 3 ----
#pragma unroll
    for (int mt = 0; mt < 2; ++mt)
#pragma unroll
        for (int j = 0; j < 4; ++j)
            accg[mt][j] = __builtin_amdgcn_mfma_f32_16x16x32_bf16(a[mt][3], bw1[j], accg[mt][j], 0, 0, 0);

    // finish scale reduction: all 64 lanes end with sum over 512 partials
#pragma unroll
    for (int off = 32; off > 0; off >>= 1) psum += __shfl_xor(psum, off, 64);
    const float sc = psum;

#pragma unroll
    for (int j = 0; j < 4; ++j) {
        const int o = j * 16 + l15;
        const float bn = biasn[(size_t)n * 64 + o];
        const float lb = lin_b[o];
#pragma unroll
        for (int mt = 0; mt < 2; ++mt)
#pragma unroll
            for (int r = 0; r < 4; ++r) {
                const int b = mt * 16 + (lane >> 4) * 4 + r;
                const float gg = accg[mt][j][r] + bn;
                const float xs = sc * accs[mt][j][r] + lb;
                out[((size_t)b * Ndim + n) * 64 + o] = gg + xs / (1.f + __expf(-xs));
            }
    }
}

// ---------------------------------------------------------------------------
extern "C" void kernel_launch(void* const* d_in, const int* in_sizes, int n_in,
                              void* d_out, int out_size, void* d_ws, size_t ws_size,
                              hipStream_t stream) {
    const float* x         = (const float*)d_in[0];
    const float* E         = (const float*)d_in[1];
    const float* pool      = (const float*)d_in[2];
    const float* bias_pool = (const float*)d_in[3];
    const float* lin_w     = (const float*)d_in[4];
    const float* lin_b     = (const float*)d_in[5];
    const float* adj       = (const float*)d_in[6];
    float* out = (float*)d_out;

    uint8_t* ws = (uint8_t*)d_ws;
    uint16_t* A      = (uint16_t*)(ws);                 // 4096*4096*2  = 32 MiB
    uint16_t* Xtt    = (uint16_t*)(ws + 33554432);      // 2048*4096*2  = 16 MiB
    uint16_t* XG     = (uint16_t*)(ws + 50331648);      // 4096*2048*2  = 16 MiB
    uint16_t* Wt     = (uint16_t*)(ws + 67108864);      // 4096*8192*2  = 64 MiB
    float*    biasn  = (float*)   (ws + 134217728);     // 4096*64*4    = 1 MiB
    float*    sd     = (float*)   (ws + 135266304);     // 16 KiB
    float*    poolT  = (float*)   (ws + 135299072);     // 512 KiB
    float*    invA   = (float*)   (ws + 135823360);     // 16 KiB
    float*    rs4    = (float*)   (ws + 135839744);     // 64 KiB
    float*    pscale = (float*)   (ws + 135905280);     // 512*4096*4 = 8 MiB

    p1_prep<<<dim3(7232), dim3(256), 0, stream>>>(E, x, adj, pool, A, rs4, Xtt, sd, poolT);
    p2_mid<<<dim3(1552), dim3(256), 0, stream>>>(E, adj, sd, poolT, bias_pool, pscale, Wt, biasn, rs4, invA);
    k3_gemm<<<dim3(512), dim3(256), 0, stream>>>(A, Xtt, invA, XG);
    k6_gconv<<<dim3(1024), dim3(256), 0, stream>>>(x, XG, Wt, biasn, pscale, lin_w, lin_b, out);
}